// Round 1
// 6285.011 us; speedup vs baseline: 1.1666x; 1.1666x over previous
//
#include <hip/hip_runtime.h>
#include <cstdint>
#include <cstddef>

typedef unsigned short u16;
typedef unsigned int u32;
typedef __attribute__((ext_vector_type(8))) short bfrag8;   // 8 bf16 = 4 VGPRs
typedef __attribute__((ext_vector_type(4))) float f32x4;

#define NB 64      // batch
#define NT 512     // timesteps
#define NE 256     // embedding dim
#define NH 512     // hidden dim
#define NWG 128    // compute workgroups (4 units x 4 gates = 16 cols each)

__device__ __forceinline__ float bf2f(u16 b) { return __uint_as_float(((unsigned)b) << 16); }
__device__ __forceinline__ u16 f2bf(float f) {
  unsigned u = __float_as_uint(f);
  u += 0x7fffu + ((u >> 16) & 1u);   // round-to-nearest-even
  return (u16)(u >> 16);
}
__device__ __forceinline__ float fsigm(float x) { return 1.0f / (1.0f + __expf(-x)); }
__device__ __forceinline__ float ftanh(float x) { return 2.0f / (1.0f + __expf(-2.0f * x)) - 1.0f; }

// split fp32 -> (hi, lo) bf16 pair; hi + lo == v to ~2^-18 relative
__device__ __forceinline__ void split1(float v, u16& h, u16& l) {
  h = f2bf(v);
  float r = v - bf2f(h);
  l = f2bf(r);
}
__device__ __forceinline__ void split8(const float* p, bfrag8& hi, bfrag8& lo) {
#pragma unroll
  for (int i = 0; i < 8; ++i) {
    u16 h, l; split1(p[i], h, l);
    hi[i] = (short)h; lo[i] = (short)l;
  }
}

__device__ __forceinline__ void unpack8(uint4 q, float* o) {
  o[0] = __uint_as_float(q.x << 16); o[1] = __uint_as_float(q.x & 0xffff0000u);
  o[2] = __uint_as_float(q.y << 16); o[3] = __uint_as_float(q.y & 0xffff0000u);
  o[4] = __uint_as_float(q.z << 16); o[5] = __uint_as_float(q.z & 0xffff0000u);
  o[6] = __uint_as_float(q.w << 16); o[7] = __uint_as_float(q.w & 0xffff0000u);
}

// ---------------- prologue: pre-split weights into per-lane fragment layout ----
// wbuf[wg][lane][48] bfrag8: [0..15]=Wh hi, [16..31]=Wh lo, [32..39]=Wi hi,
// [40..47]=Wi lo -- exactly the order the step loop's lane (colq=lane&15,
// koff=(lane>>4)*8) consumes. bias_s[wg][16] = bh+bi fused.
__global__ __launch_bounds__(64) void stage_weights(
    const float* __restrict__ Whr, const float* __restrict__ Whf,
    const float* __restrict__ Whg, const float* __restrict__ Who,
    const float* __restrict__ Wir, const float* __restrict__ Wif,
    const float* __restrict__ Wig, const float* __restrict__ Wio,
    const float* __restrict__ bhr, const float* __restrict__ bhf,
    const float* __restrict__ bhg, const float* __restrict__ bho,
    const float* __restrict__ bir, const float* __restrict__ bif,
    const float* __restrict__ big_, const float* __restrict__ bio,
    u16* __restrict__ wbuf, float* __restrict__ bias_s)
{
  const int wg = blockIdx.x;
  const int lane = threadIdx.x;
  const int colq = lane & 15;
  const int koff = (lane >> 4) * 8;
  const int gate = colq >> 2;
  const int gu = wg * 4 + (colq & 3);
  const float* wh = (gate == 0) ? Whr : (gate == 1) ? Whf : (gate == 2) ? Whg : Who;
  const float* wi = (gate == 0) ? Wir : (gate == 1) ? Wif : (gate == 2) ? Wig : Wio;
  u16* wb = wbuf + (size_t)(wg * 64 + lane) * 48 * 8;
  const float* whp = wh + (size_t)gu * NH + koff;
  const float* wip = wi + (size_t)gu * NE + koff;
#pragma unroll
  for (int kt = 0; kt < 16; ++kt) {
    bfrag8 hi, lo; split8(whp + kt * 32, hi, lo);
    *(bfrag8*)(wb + kt * 8) = hi;
    *(bfrag8*)(wb + (16 + kt) * 8) = lo;
  }
#pragma unroll
  for (int kt = 0; kt < 8; ++kt) {
    bfrag8 hi, lo; split8(wip + kt * 32, hi, lo);
    *(bfrag8*)(wb + (32 + kt) * 8) = hi;
    *(bfrag8*)(wb + (40 + kt) * 8) = lo;
  }
  if (lane < 16) {
    int g2 = lane >> 2, u2 = lane & 3, gu2 = wg * 4 + u2;
    const float* bh = (g2 == 0) ? bhr : (g2 == 1) ? bhf : (g2 == 2) ? bhg : bho;
    const float* bi = (g2 == 0) ? bir : (g2 == 1) ? bif : (g2 == 2) ? big_ : bio;
    bias_s[wg * 16 + lane] = bh[gu2] + bi[gu2];
  }
}

// ---------------- persistent LSTM: all 512 steps in ONE kernel ----------------
// 128 blocks x 256 threads (<= 256 CUs, launch_bounds(256,1) => co-resident).
// Per-step sync: per-wave vmcnt drain -> syncthreads -> wave0 agent-release
// fence (wbl2) -> one fetch_add arrival per block at MALL; last arriver posts
// the step ticket bar[32]. Waiters: tid0 relaxed-spins the ticket, agent-
// acquire fence (buffer_inv), syncthreads. h is double-buffered in global
// (normal cached loads: post-inv they L2-share within an XCD). Weights live
// in LDS (inv-immune); cell state lives in a register (thread owns its (b,u)
// cell for all 512 steps). Math/order is bit-identical to the per-step kernel.
__global__ __launch_bounds__(256, 1) void lstm_persist(
    const int* __restrict__ words,
    const float* __restrict__ emb,
    const u16* __restrict__ wbuf,
    const float* __restrict__ bias_s,
    u32* __restrict__ hbuf,     // [2][B][H] packed hi|lo
    u16* __restrict__ hs_all,   // [T][B][H] bf16 (attention path)
    float* __restrict__ hlast,  // [B][H] fp32 final h
    u32* bar)                   // bar[0]=arrival count, bar[32]=done ticket
{
  const int wg = blockIdx.x;
  const int tid = threadIdx.x;
  const int lane = tid & 63;
  const int wave = tid >> 6;
  const int mbase = wave * 16;
  const int colq = lane & 15;
  const int koff = (lane >> 4) * 8;
  const int arow = mbase + colq;            // batch row for A fragments

  // per-lane weight block: 48 bfrag8 = 768B, padded to 784B (49x16B) so lane
  // stride is 196 dwords == 4 (mod 32) -> b128 reads spread across all banks
  __shared__ u16 wlds[64 * 392];
  __shared__ float gatesLds[NB * 17];       // per-wave rows; intra-wave only
  __shared__ float biasLds[16];

  if (wave == 0) {
    const u16* src = wbuf + (size_t)(wg * 64 + lane) * 384;
    u16* dst = wlds + lane * 392;
#pragma unroll
    for (int i = 0; i < 48; ++i)
      *(bfrag8*)(dst + i * 8) = *(const bfrag8*)(src + i * 8);
  }
  if (tid < 16) biasLds[tid] = bias_s[wg * 16 + tid];
  __syncthreads();

  const bool is64 = ((words[1] | words[3] | words[5] | words[7]) == 0);
  const int b_own = tid >> 2, u_own = tid & 3;
  float creg = 0.0f;                        // cell state: register-resident

  // preamble: emb gather for t=1
  f32x4 xa[8], xb[8];
  {
    int widx = arow * NT + 0;
    int w = is64 ? words[2 * widx] : words[widx];
    const float* xs = emb + (size_t)w * NE + koff;
#pragma unroll
    for (int kt = 0; kt < 8; ++kt) {
      xa[kt] = *(const f32x4*)(xs + kt * 32);
      xb[kt] = *(const f32x4*)(xs + kt * 32 + 4);
    }
  }

  const u16* wl = wlds + lane * 392;

  for (int t = 1; t <= NT; ++t) {
    // ---- wait for step t-1 to be globally visible ----
    if (t > 1) {
      if (tid == 0) {
        while (__hip_atomic_load(&bar[32], __ATOMIC_RELAXED, __HIP_MEMORY_SCOPE_AGENT) < (u32)(t - 1))
          __builtin_amdgcn_s_sleep(1);
        __builtin_amdgcn_fence(__ATOMIC_ACQUIRE, "agent");   // buffer_inv (L2 clean)
      }
      __syncthreads();
      asm volatile("" ::: "memory");        // no mem op crosses (compiler)
    }

    f32x4 acc = {0.f, 0.f, 0.f, 0.f};

    // ---- h MFMAs (hi/lo 3-term, fp32-equivalent) ----
    if (t > 1) {
      const u32* hp = hbuf + ((size_t)((t - 1) & 1) * NB + arow) * NH + koff;
      uint4 hq0[16], hq1[16];
#pragma unroll
      for (int kt = 0; kt < 16; ++kt) {
        hq0[kt] = *(const uint4*)(hp + kt * 32);
        hq1[kt] = *(const uint4*)(hp + kt * 32 + 4);
      }
#pragma unroll
      for (int kt = 0; kt < 16; ++kt) {
        bfrag8 ah, al;
        uint4 q0 = hq0[kt], q1 = hq1[kt];
        ah[0] = (short)(q0.x >> 16); al[0] = (short)(q0.x & 0xffffu);
        ah[1] = (short)(q0.y >> 16); al[1] = (short)(q0.y & 0xffffu);
        ah[2] = (short)(q0.z >> 16); al[2] = (short)(q0.z & 0xffffu);
        ah[3] = (short)(q0.w >> 16); al[3] = (short)(q0.w & 0xffffu);
        ah[4] = (short)(q1.x >> 16); al[4] = (short)(q1.x & 0xffffu);
        ah[5] = (short)(q1.y >> 16); al[5] = (short)(q1.y & 0xffffu);
        ah[6] = (short)(q1.z >> 16); al[6] = (short)(q1.z & 0xffffu);
        ah[7] = (short)(q1.w >> 16); al[7] = (short)(q1.w & 0xffffu);
        bfrag8 whh = *(const bfrag8*)(wl + kt * 8);
        bfrag8 whl = *(const bfrag8*)(wl + (16 + kt) * 8);
        acc = __builtin_amdgcn_mfma_f32_16x16x32_bf16(ah, whh, acc, 0, 0, 0);
        acc = __builtin_amdgcn_mfma_f32_16x16x32_bf16(al, whh, acc, 0, 0, 0);
        acc = __builtin_amdgcn_mfma_f32_16x16x32_bf16(ah, whl, acc, 0, 0, 0);
      }
    }

    // ---- X MFMAs (emb split on the fly; emb gathered last iteration) ----
#pragma unroll
    for (int kt = 0; kt < 8; ++kt) {
      bfrag8 xh, xl;
#pragma unroll
      for (int i = 0; i < 4; ++i) {
        u16 h, l;
        split1(xa[kt][i], h, l); xh[i] = (short)h; xl[i] = (short)l;
        split1(xb[kt][i], h, l); xh[4 + i] = (short)h; xl[4 + i] = (short)l;
      }
      bfrag8 wih = *(const bfrag8*)(wl + (32 + kt) * 8);
      bfrag8 wil = *(const bfrag8*)(wl + (40 + kt) * 8);
      acc = __builtin_amdgcn_mfma_f32_16x16x32_bf16(xh, wih, acc, 0, 0, 0);
      acc = __builtin_amdgcn_mfma_f32_16x16x32_bf16(xl, wih, acc, 0, 0, 0);
      acc = __builtin_amdgcn_mfma_f32_16x16x32_bf16(xh, wil, acc, 0, 0, 0);
    }

    // ---- intra-wave transpose via LDS (wave's own rows; no barrier) ----
    {
      int drow = mbase + ((lane >> 4) << 2);
#pragma unroll
      for (int r = 0; r < 4; ++r) gatesLds[(drow + r) * 17 + colq] = acc[r];
    }

    // ---- gate math; thread owns one (b,u) in its own wave's rows ----
    {
      const float* gl = &gatesLds[b_own * 17];
      float xr = gl[u_own]      + biasLds[u_own];
      float xf = gl[4 + u_own]  + biasLds[4 + u_own];
      float xg = gl[8 + u_own]  + biasLds[8 + u_own];
      float xo = gl[12 + u_own] + biasLds[12 + u_own];
      float rg = fsigm(xr), fg = fsigm(xf), gg = ftanh(xg), og = fsigm(xo);
      creg = fg * creg + rg * gg;
      float hv = og * ftanh(creg);
      u16 hhi, hlo; split1(hv, hhi, hlo);
      int ci = b_own * NH + wg * 4 + u_own;
      hbuf[((size_t)(t & 1) * NB + b_own) * NH + wg * 4 + u_own] = ((u32)hhi << 16) | (u32)hlo;
      hs_all[(size_t)(t - 1) * (NB * NH) + ci] = hhi;
      if (t == NT) hlast[ci] = hv;
    }

    // ---- signal: stores -> L2 (per wave), wbl2 once, one arrival per block --
    asm volatile("s_waitcnt vmcnt(0)" ::: "memory");
    __syncthreads();
    if (tid == 0) {
      __builtin_amdgcn_fence(__ATOMIC_RELEASE, "agent");     // wbl2: dirty L2 -> MALL
      u32 old = __hip_atomic_fetch_add(&bar[0], 1u, __ATOMIC_RELAXED, __HIP_MEMORY_SCOPE_AGENT);
      if (old == (u32)NWG * (u32)t - 1u)
        __hip_atomic_store(&bar[32], (u32)t, __ATOMIC_RELAXED, __HIP_MEMORY_SCOPE_AGENT);
    }

    // ---- slack window: emb gather for t+1 (registers survive the inv) ----
    if (t < NT) {
      int widx = arow * NT + t;
      int w = is64 ? words[2 * widx] : words[widx];
      const float* xs = emb + (size_t)w * NE + koff;
#pragma unroll
      for (int kt = 0; kt < 8; ++kt) {
        xa[kt] = *(const f32x4*)(xs + kt * 32);
        xb[kt] = *(const f32x4*)(xs + kt * 32 + 4);
      }
    }
  }
}

// ---------------- attention + output head (one WG per batch) ----------------
__global__ __launch_bounds__(256) void post_kernel(
    const float* __restrict__ hlast,  // [B][H] fp32
    const u16* __restrict__ hs,       // [T][B][H] bf16
    const float* __restrict__ W_ol, const float* __restrict__ b_ol,   // [256][512], [256]
    const float* __restrict__ W_att, const float* __restrict__ b_att, // [256][512], [512]
    const float* __restrict__ W_fc, const float* __restrict__ b_fc,   // [2][768], [2]
    float* __restrict__ out)          // [64*2] ++ [64*512] fp32
{
  int b = blockIdx.x, tid = threadIdx.x;
  __shared__ float hl[NH], fh[256], sc[NH], att[NT], ao[NH], red[256];

  for (int i = tid; i < NH; i += 256) {
    float hv = hlast[b * NH + i];
    hl[i] = hv;
    out[128 + b * NH + i] = hv;   // output 1: h_last
  }
  __syncthreads();

  // final_hidden[j] = b_ol[j] + hl . W_ol[j][:]
  {
    float s = b_ol[tid];
    const float* w = W_ol + (size_t)tid * NH;
    for (int k = 0; k < NH; k += 4) {
      f32x4 q = *(const f32x4*)(w + k);
      s += q[0] * hl[k] + q[1] * hl[k + 1] + q[2] * hl[k + 2] + q[3] * hl[k + 3];
    }
    fh[tid] = s;
  }
  __syncthreads();

  // score[h] = b_att[h] + sum_j fh[j] * W_att[j][h]
  for (int h = tid; h < NH; h += 256) {
    float s = b_att[h];
    for (int j = 0; j < 256; ++j) s += fh[j] * W_att[(size_t)j * NH + h];
    sc[h] = s;
  }
  __syncthreads();

  // att[t] = score . hs[t][b][:]
  for (int t = tid; t < NT; t += 256) {
    const u16* row = hs + ((size_t)t * NB + b) * NH;
    float s = 0.f;
    for (int k = 0; k < NH; k += 8) {
      uint4 q = *(const uint4*)(row + k);
      float tmp[8]; unpack8(q, tmp);
#pragma unroll
      for (int j = 0; j < 8; ++j) s += tmp[j] * sc[k + j];
    }
    att[t] = s;
  }
  __syncthreads();

  // softmax over T
  float l0 = att[tid], l1 = att[tid + 256];
  red[tid] = fmaxf(l0, l1);
  __syncthreads();
  for (int s = 128; s > 0; s >>= 1) { if (tid < s) red[tid] = fmaxf(red[tid], red[tid + s]); __syncthreads(); }
  float mx = red[0];
  __syncthreads();
  float e0 = __expf(l0 - mx), e1 = __expf(l1 - mx);
  red[tid] = e0 + e1;
  __syncthreads();
  for (int s = 128; s > 0; s >>= 1) { if (tid < s) red[tid] += red[tid + s]; __syncthreads(); }
  float inv = 1.0f / red[0];
  __syncthreads();
  att[tid] = e0 * inv;
  att[tid + 256] = e1 * inv;
  __syncthreads();

  // att_out[h] = sum_t dist[t] * hs[t][b][h]
  {
    float a0 = 0.f, a1 = 0.f;
    for (int t = 0; t < NT; ++t) {
      float d = att[t];
      const u16* row = hs + ((size_t)t * NB + b) * NH;
      a0 += d * bf2f(row[tid]);
      a1 += d * bf2f(row[tid + 256]);
    }
    ao[tid] = a0;
    ao[tid + 256] = a1;
  }
  __syncthreads();

  // out[o] = sigmoid(b_fc[o] + [fh, ao] . W_fc[o][:])
#pragma unroll
  for (int o = 0; o < 2; ++o) {
    float part = 0.f;
    for (int i = tid; i < 768; i += 256) {
      float v = (i < 256) ? fh[i] : ao[i - 256];
      part += v * W_fc[o * 768 + i];
    }
    red[tid] = part;
    __syncthreads();
    for (int s = 128; s > 0; s >>= 1) { if (tid < s) red[tid] += red[tid + s]; __syncthreads(); }
    if (tid == 0) out[b * 2 + o] = fsigm(red[0] + b_fc[o]);
    __syncthreads();
  }
}

// ---------------- host launch: memset(bar) + stage + 1 persistent + post ----
extern "C" void kernel_launch(void* const* d_in, const int* in_sizes, int n_in,
                              void* d_out, int out_size, void* d_ws, size_t ws_size,
                              hipStream_t stream) {
  const int* words  = (const int*)d_in[0];
  const float* emb  = (const float*)d_in[1];
  const float* Wir  = (const float*)d_in[2];  const float* bir = (const float*)d_in[3];
  const float* Whr  = (const float*)d_in[4];  const float* bhr = (const float*)d_in[5];
  const float* Wif  = (const float*)d_in[6];  const float* bif = (const float*)d_in[7];
  const float* Whf  = (const float*)d_in[8];  const float* bhf = (const float*)d_in[9];
  const float* Wig  = (const float*)d_in[10]; const float* big_ = (const float*)d_in[11];
  const float* Whg  = (const float*)d_in[12]; const float* bhg = (const float*)d_in[13];
  const float* Wio  = (const float*)d_in[14]; const float* bio = (const float*)d_in[15];
  const float* Who  = (const float*)d_in[16]; const float* bho = (const float*)d_in[17];
  const float* W_att = (const float*)d_in[18]; const float* b_att = (const float*)d_in[19];
  const float* W_ol  = (const float*)d_in[20]; const float* b_ol  = (const float*)d_in[21];
  const float* W_fc  = (const float*)d_in[22]; const float* b_fc  = (const float*)d_in[23];

  uint8_t* ws = (uint8_t*)d_ws;
  u16* hs       = (u16*)ws;                              // 512*64*512*2 = 32 MiB
  size_t off    = (size_t)33554432;
  u16* wbuf     = (u16*)(ws + off);   off += 6291456;    // 128*64*48*16B = 6 MiB
  float* bias_s = (float*)(ws + off); off += 8192;       // 128*16*4
  u32* hbuf     = (u32*)(ws + off);   off += 262144;     // 2*64*512*4
  float* hlast  = (float*)(ws + off); off += 131072;     // 64*512*4
  u32* bar      = (u32*)(ws + off);                      // 256B barrier state

  hipMemsetAsync(bar, 0, 256, stream);                   // reset per launch/replay

  stage_weights<<<dim3(NWG), dim3(64), 0, stream>>>(
      Whr, Whf, Whg, Who, Wir, Wif, Wig, Wio,
      bhr, bhf, bhg, bho, bir, bif, big_, bio, wbuf, bias_s);

  lstm_persist<<<dim3(NWG), dim3(256), 0, stream>>>(
      words, emb, wbuf, bias_s, hbuf, hs, hlast, bar);

  post_kernel<<<dim3(NB), dim3(256), 0, stream>>>(hlast, hs, W_ol, b_ol, W_att, b_att,
                                                  W_fc, b_fc, (float*)d_out);
}

// Round 2
// 5792.933 us; speedup vs baseline: 1.2657x; 1.0849x over previous
//
#include <hip/hip_runtime.h>
#include <cstdint>
#include <cstddef>

typedef unsigned short u16;
typedef unsigned int u32;
typedef unsigned long long u64;
typedef __attribute__((ext_vector_type(8))) short bfrag8;   // 8 bf16 = 4 VGPRs
typedef __attribute__((ext_vector_type(4))) float f32x4;

#define NB 64      // batch
#define NT 512     // timesteps
#define NE 256     // embedding dim
#define NH 512     // hidden dim
#define NWG 128    // compute workgroups (4 units x 4 gates = 16 cols each)

__device__ __forceinline__ float bf2f(u16 b) { return __uint_as_float(((unsigned)b) << 16); }
__device__ __forceinline__ u16 f2bf(float f) {
  unsigned u = __float_as_uint(f);
  u += 0x7fffu + ((u >> 16) & 1u);   // round-to-nearest-even
  return (u16)(u >> 16);
}
__device__ __forceinline__ float fsigm(float x) { return 1.0f / (1.0f + __expf(-x)); }
__device__ __forceinline__ float ftanh(float x) { return 2.0f / (1.0f + __expf(-2.0f * x)) - 1.0f; }

// split fp32 -> (hi, lo) bf16 pair; hi + lo == v to ~2^-18 relative
__device__ __forceinline__ void split1(float v, u16& h, u16& l) {
  h = f2bf(v);
  float r = v - bf2f(h);
  l = f2bf(r);
}
__device__ __forceinline__ void split8(const float* p, bfrag8& hi, bfrag8& lo) {
#pragma unroll
  for (int i = 0; i < 8; ++i) {
    u16 h, l; split1(p[i], h, l);
    hi[i] = (short)h; lo[i] = (short)l;
  }
}

__device__ __forceinline__ void unpack8(uint4 q, float* o) {
  o[0] = __uint_as_float(q.x << 16); o[1] = __uint_as_float(q.x & 0xffff0000u);
  o[2] = __uint_as_float(q.y << 16); o[3] = __uint_as_float(q.y & 0xffff0000u);
  o[4] = __uint_as_float(q.z << 16); o[5] = __uint_as_float(q.z & 0xffff0000u);
  o[6] = __uint_as_float(q.w << 16); o[7] = __uint_as_float(q.w & 0xffff0000u);
}

// ---------------- prologue: pre-split weights into per-lane fragment layout ----
__global__ __launch_bounds__(64) void stage_weights(
    const float* __restrict__ Whr, const float* __restrict__ Whf,
    const float* __restrict__ Whg, const float* __restrict__ Who,
    const float* __restrict__ Wir, const float* __restrict__ Wif,
    const float* __restrict__ Wig, const float* __restrict__ Wio,
    const float* __restrict__ bhr, const float* __restrict__ bhf,
    const float* __restrict__ bhg, const float* __restrict__ bho,
    const float* __restrict__ bir, const float* __restrict__ bif,
    const float* __restrict__ big_, const float* __restrict__ bio,
    u16* __restrict__ wbuf, float* __restrict__ bias_s)
{
  const int wg = blockIdx.x;
  const int lane = threadIdx.x;
  const int colq = lane & 15;
  const int koff = (lane >> 4) * 8;
  const int gate = colq >> 2;
  const int gu = wg * 4 + (colq & 3);
  const float* wh = (gate == 0) ? Whr : (gate == 1) ? Whf : (gate == 2) ? Whg : Who;
  const float* wi = (gate == 0) ? Wir : (gate == 1) ? Wif : (gate == 2) ? Wig : Wio;
  u16* wb = wbuf + (size_t)(wg * 64 + lane) * 48 * 8;
  const float* whp = wh + (size_t)gu * NH + koff;
  const float* wip = wi + (size_t)gu * NE + koff;
#pragma unroll
  for (int kt = 0; kt < 16; ++kt) {
    bfrag8 hi, lo; split8(whp + kt * 32, hi, lo);
    *(bfrag8*)(wb + kt * 8) = hi;
    *(bfrag8*)(wb + (16 + kt) * 8) = lo;
  }
#pragma unroll
  for (int kt = 0; kt < 8; ++kt) {
    bfrag8 hi, lo; split8(wip + kt * 32, hi, lo);
    *(bfrag8*)(wb + (32 + kt) * 8) = hi;
    *(bfrag8*)(wb + (40 + kt) * 8) = lo;
  }
  if (lane < 16) {
    int g2 = lane >> 2, u2 = lane & 3, gu2 = wg * 4 + u2;
    const float* bh = (g2 == 0) ? bhr : (g2 == 1) ? bhf : (g2 == 2) ? bhg : bho;
    const float* bi = (g2 == 0) ? bir : (g2 == 1) ? bif : (g2 == 2) ? big_ : bio;
    bias_s[wg * 16 + lane] = bh[gu2] + bi[gu2];
  }
}

// ---------------- persistent LSTM: all 512 steps in ONE kernel ----------------
// Cross-block h exchange goes through MALL ONLY (agent-scope relaxed atomics =
// sc0 sc1 ops): no wbl2/inv fences, so L2 keeps emb/words/weights warm for all
// 512 steps. Barrier = flat slot array: block wg stores bar[wg]=t after its
// stores drained (__syncthreads implies vmcnt(0)); every block's wave 0 polls
// all 128 slots (2 loads/lane + __all) -- fully parallel, no RMW chain, no
// ticket hop. Double-buffered h + full per-step barrier make buffer reuse safe.
// Math/order is bit-identical to the previous version.
__global__ __launch_bounds__(256, 1) void lstm_persist(
    const int* __restrict__ words,
    const float* __restrict__ emb,
    const u16* __restrict__ wbuf,
    const float* __restrict__ bias_s,
    u32* __restrict__ hbuf,     // [2][B][H] packed hi|lo (MALL-coherent)
    u16* __restrict__ hs_all,   // [T][B][H] bf16 (attention path, cached)
    float* __restrict__ hlast,  // [B][H] fp32 final h
    u32* bar)                   // bar[0..127] = per-block step slot
{
  const int wg = blockIdx.x;
  const int tid = threadIdx.x;
  const int lane = tid & 63;
  const int wave = tid >> 6;
  const int mbase = wave * 16;
  const int colq = lane & 15;
  const int koff = (lane >> 4) * 8;
  const int arow = mbase + colq;            // batch row for A fragments

  // per-lane weight block: 48 bfrag8 = 768B, padded to 784B (49x16B) so lane
  // stride is 196 dwords == 4 (mod 32) -> b128 reads spread across all banks
  __shared__ u16 wlds[64 * 392];
  __shared__ float gatesLds[NB * 17];       // per-wave rows; intra-wave only
  __shared__ float biasLds[16];

  if (wave == 0) {
    const u16* src = wbuf + (size_t)(wg * 64 + lane) * 384;
    u16* dst = wlds + lane * 392;
#pragma unroll
    for (int i = 0; i < 48; ++i)
      *(bfrag8*)(dst + i * 8) = *(const bfrag8*)(src + i * 8);
  }
  if (tid < 16) biasLds[tid] = bias_s[wg * 16 + tid];
  __syncthreads();

  const bool is64 = ((words[1] | words[3] | words[5] | words[7]) == 0);
  const int b_own = tid >> 2, u_own = tid & 3;
  float creg = 0.0f;                        // cell state: register-resident

  // preamble: emb gather for t=1 (normal cached loads; L2 stays warm)
  f32x4 xa[8], xb[8];
  {
    int widx = arow * NT + 0;
    int w = is64 ? words[2 * widx] : words[widx];
    const float* xs = emb + (size_t)w * NE + koff;
#pragma unroll
    for (int kt = 0; kt < 8; ++kt) {
      xa[kt] = *(const f32x4*)(xs + kt * 32);
      xb[kt] = *(const f32x4*)(xs + kt * 32 + 4);
    }
  }

  const u16* wl = wlds + lane * 392;

  for (int t = 1; t <= NT; ++t) {
    // ---- wait: all blocks posted slot >= t-1 (parallel distributed poll) ----
    if (t > 1) {
      if (wave == 0) {
        const u32 need = (u32)(t - 1);
        u32 a, b;
        do {
          a = __hip_atomic_load(&bar[2 * lane],     __ATOMIC_RELAXED, __HIP_MEMORY_SCOPE_AGENT);
          b = __hip_atomic_load(&bar[2 * lane + 1], __ATOMIC_RELAXED, __HIP_MEMORY_SCOPE_AGENT);
        } while (!__all((int)(a >= need && b >= need)));
      }
      __syncthreads();
      asm volatile("" ::: "memory");        // nothing crosses (compiler)
    }

    f32x4 acc = {0.f, 0.f, 0.f, 0.f};

    // ---- h MFMAs (hi/lo 3-term, fp32-equivalent); loads read MALL directly --
    if (t > 1) {
      const u64* hp64 = (const u64*)(hbuf + ((size_t)((t - 1) & 1) * NB + arow) * NH + koff);
      u64 hv[64];
#pragma unroll
      for (int kt = 0; kt < 16; ++kt) {
#pragma unroll
        for (int j = 0; j < 4; ++j)
          hv[kt * 4 + j] = __hip_atomic_load(&hp64[kt * 16 + j], __ATOMIC_RELAXED, __HIP_MEMORY_SCOPE_AGENT);
      }
#pragma unroll
      for (int kt = 0; kt < 16; ++kt) {
        u64 qa = hv[kt * 4 + 0], qb = hv[kt * 4 + 1];
        u64 qc = hv[kt * 4 + 2], qd = hv[kt * 4 + 3];
        u32 w0 = (u32)qa, w1 = (u32)(qa >> 32);
        u32 w2 = (u32)qb, w3 = (u32)(qb >> 32);
        u32 w4 = (u32)qc, w5 = (u32)(qc >> 32);
        u32 w6 = (u32)qd, w7 = (u32)(qd >> 32);
        bfrag8 ah, al;
        ah[0] = (short)(w0 >> 16); al[0] = (short)(w0 & 0xffffu);
        ah[1] = (short)(w1 >> 16); al[1] = (short)(w1 & 0xffffu);
        ah[2] = (short)(w2 >> 16); al[2] = (short)(w2 & 0xffffu);
        ah[3] = (short)(w3 >> 16); al[3] = (short)(w3 & 0xffffu);
        ah[4] = (short)(w4 >> 16); al[4] = (short)(w4 & 0xffffu);
        ah[5] = (short)(w5 >> 16); al[5] = (short)(w5 & 0xffffu);
        ah[6] = (short)(w6 >> 16); al[6] = (short)(w6 & 0xffffu);
        ah[7] = (short)(w7 >> 16); al[7] = (short)(w7 & 0xffffu);
        bfrag8 whh = *(const bfrag8*)(wl + kt * 8);
        bfrag8 whl = *(const bfrag8*)(wl + (16 + kt) * 8);
        acc = __builtin_amdgcn_mfma_f32_16x16x32_bf16(ah, whh, acc, 0, 0, 0);
        acc = __builtin_amdgcn_mfma_f32_16x16x32_bf16(al, whh, acc, 0, 0, 0);
        acc = __builtin_amdgcn_mfma_f32_16x16x32_bf16(ah, whl, acc, 0, 0, 0);
      }
    }

    // ---- X MFMAs (emb split on the fly; emb gathered last iteration) ----
#pragma unroll
    for (int kt = 0; kt < 8; ++kt) {
      bfrag8 xh, xl;
#pragma unroll
      for (int i = 0; i < 4; ++i) {
        u16 h, l;
        split1(xa[kt][i], h, l); xh[i] = (short)h; xl[i] = (short)l;
        split1(xb[kt][i], h, l); xh[4 + i] = (short)h; xl[4 + i] = (short)l;
      }
      bfrag8 wih = *(const bfrag8*)(wl + (32 + kt) * 8);
      bfrag8 wil = *(const bfrag8*)(wl + (40 + kt) * 8);
      acc = __builtin_amdgcn_mfma_f32_16x16x32_bf16(xh, wih, acc, 0, 0, 0);
      acc = __builtin_amdgcn_mfma_f32_16x16x32_bf16(xl, wih, acc, 0, 0, 0);
      acc = __builtin_amdgcn_mfma_f32_16x16x32_bf16(xh, wil, acc, 0, 0, 0);
    }

    // ---- intra-wave transpose via LDS (wave's own rows; no barrier) ----
    {
      int drow = mbase + ((lane >> 4) << 2);
#pragma unroll
      for (int r = 0; r < 4; ++r) gatesLds[(drow + r) * 17 + colq] = acc[r];
    }

    // ---- gate math; thread owns one (b,u) in its own wave's rows ----
    {
      const float* gl = &gatesLds[b_own * 17];
      float xr = gl[u_own]      + biasLds[u_own];
      float xf = gl[4 + u_own]  + biasLds[4 + u_own];
      float xg = gl[8 + u_own]  + biasLds[8 + u_own];
      float xo = gl[12 + u_own] + biasLds[12 + u_own];
      float rg = fsigm(xr), fg = fsigm(xf), gg = ftanh(xg), og = fsigm(xo);
      creg = fg * creg + rg * gg;
      float hv = og * ftanh(creg);
      u16 hhi, hlo; split1(hv, hhi, hlo);
      int ci = b_own * NH + wg * 4 + u_own;
      u32 packed = ((u32)hhi << 16) | (u32)hlo;
      __hip_atomic_store(&hbuf[((size_t)(t & 1) * NB + b_own) * NH + wg * 4 + u_own],
                         packed, __ATOMIC_RELAXED, __HIP_MEMORY_SCOPE_AGENT);
      hs_all[(size_t)(t - 1) * (NB * NH) + ci] = hhi;
      if (t == NT) hlast[ci] = hv;
    }

    // ---- arrive: __syncthreads drains every wave's vmcnt (stores at MALL),
    //      then one slot store per block. No fences, no RMW chain. ----
    __syncthreads();
    if (tid == 0)
      __hip_atomic_store(&bar[wg], (u32)t, __ATOMIC_RELAXED, __HIP_MEMORY_SCOPE_AGENT);

    // ---- slack window: emb gather for t+1 (L2-warm; overlaps remote polls) --
    if (t < NT) {
      int widx = arow * NT + t;
      int w = is64 ? words[2 * widx] : words[widx];
      const float* xs = emb + (size_t)w * NE + koff;
#pragma unroll
      for (int kt = 0; kt < 8; ++kt) {
        xa[kt] = *(const f32x4*)(xs + kt * 32);
        xb[kt] = *(const f32x4*)(xs + kt * 32 + 4);
      }
    }
  }
}

// ---------------- attention + output head (one WG per batch) ----------------
__global__ __launch_bounds__(256) void post_kernel(
    const float* __restrict__ hlast,  // [B][H] fp32
    const u16* __restrict__ hs,       // [T][B][H] bf16
    const float* __restrict__ W_ol, const float* __restrict__ b_ol,   // [256][512], [256]
    const float* __restrict__ W_att, const float* __restrict__ b_att, // [256][512], [512]
    const float* __restrict__ W_fc, const float* __restrict__ b_fc,   // [2][768], [2]
    float* __restrict__ out)          // [64*2] ++ [64*512] fp32
{
  int b = blockIdx.x, tid = threadIdx.x;
  __shared__ float hl[NH], fh[256], sc[NH], att[NT], ao[NH], red[256];

  for (int i = tid; i < NH; i += 256) {
    float hv = hlast[b * NH + i];
    hl[i] = hv;
    out[128 + b * NH + i] = hv;   // output 1: h_last
  }
  __syncthreads();

  // final_hidden[j] = b_ol[j] + hl . W_ol[j][:]
  {
    float s = b_ol[tid];
    const float* w = W_ol + (size_t)tid * NH;
    for (int k = 0; k < NH; k += 4) {
      f32x4 q = *(const f32x4*)(w + k);
      s += q[0] * hl[k] + q[1] * hl[k + 1] + q[2] * hl[k + 2] + q[3] * hl[k + 3];
    }
    fh[tid] = s;
  }
  __syncthreads();

  // score[h] = b_att[h] + sum_j fh[j] * W_att[j][h]
  for (int h = tid; h < NH; h += 256) {
    float s = b_att[h];
    for (int j = 0; j < 256; ++j) s += fh[j] * W_att[(size_t)j * NH + h];
    sc[h] = s;
  }
  __syncthreads();

  // att[t] = score . hs[t][b][:]
  for (int t = tid; t < NT; t += 256) {
    const u16* row = hs + ((size_t)t * NB + b) * NH;
    float s = 0.f;
    for (int k = 0; k < NH; k += 8) {
      uint4 q = *(const uint4*)(row + k);
      float tmp[8]; unpack8(q, tmp);
#pragma unroll
      for (int j = 0; j < 8; ++j) s += tmp[j] * sc[k + j];
    }
    att[t] = s;
  }
  __syncthreads();

  // softmax over T
  float l0 = att[tid], l1 = att[tid + 256];
  red[tid] = fmaxf(l0, l1);
  __syncthreads();
  for (int s = 128; s > 0; s >>= 1) { if (tid < s) red[tid] = fmaxf(red[tid], red[tid + s]); __syncthreads(); }
  float mx = red[0];
  __syncthreads();
  float e0 = __expf(l0 - mx), e1 = __expf(l1 - mx);
  red[tid] = e0 + e1;
  __syncthreads();
  for (int s = 128; s > 0; s >>= 1) { if (tid < s) red[tid] += red[tid + s]; __syncthreads(); }
  float inv = 1.0f / red[0];
  __syncthreads();
  att[tid] = e0 * inv;
  att[tid + 256] = e1 * inv;
  __syncthreads();

  // att_out[h] = sum_t dist[t] * hs[t][b][h]
  {
    float a0 = 0.f, a1 = 0.f;
    for (int t = 0; t < NT; ++t) {
      float d = att[t];
      const u16* row = hs + ((size_t)t * NB + b) * NH;
      a0 += d * bf2f(row[tid]);
      a1 += d * bf2f(row[tid + 256]);
    }
    ao[tid] = a0;
    ao[tid + 256] = a1;
  }
  __syncthreads();

  // out[o] = sigmoid(b_fc[o] + [fh, ao] . W_fc[o][:])
#pragma unroll
  for (int o = 0; o < 2; ++o) {
    float part = 0.f;
    for (int i = tid; i < 768; i += 256) {
      float v = (i < 256) ? fh[i] : ao[i - 256];
      part += v * W_fc[o * 768 + i];
    }
    red[tid] = part;
    __syncthreads();
    for (int s = 128; s > 0; s >>= 1) { if (tid < s) red[tid] += red[tid + s]; __syncthreads(); }
    if (tid == 0) out[b * 2 + o] = fsigm(red[0] + b_fc[o]);
    __syncthreads();
  }
}

// ---------------- host launch: memset(bar) + stage + 1 persistent + post ----
extern "C" void kernel_launch(void* const* d_in, const int* in_sizes, int n_in,
                              void* d_out, int out_size, void* d_ws, size_t ws_size,
                              hipStream_t stream) {
  const int* words  = (const int*)d_in[0];
  const float* emb  = (const float*)d_in[1];
  const float* Wir  = (const float*)d_in[2];  const float* bir = (const float*)d_in[3];
  const float* Whr  = (const float*)d_in[4];  const float* bhr = (const float*)d_in[5];
  const float* Wif  = (const float*)d_in[6];  const float* bif = (const float*)d_in[7];
  const float* Whf  = (const float*)d_in[8];  const float* bhf = (const float*)d_in[9];
  const float* Wig  = (const float*)d_in[10]; const float* big_ = (const float*)d_in[11];
  const float* Whg  = (const float*)d_in[12]; const float* bhg = (const float*)d_in[13];
  const float* Wio  = (const float*)d_in[14]; const float* bio = (const float*)d_in[15];
  const float* Who  = (const float*)d_in[16]; const float* bho = (const float*)d_in[17];
  const float* W_att = (const float*)d_in[18]; const float* b_att = (const float*)d_in[19];
  const float* W_ol  = (const float*)d_in[20]; const float* b_ol  = (const float*)d_in[21];
  const float* W_fc  = (const float*)d_in[22]; const float* b_fc  = (const float*)d_in[23];

  uint8_t* ws = (uint8_t*)d_ws;
  u16* hs       = (u16*)ws;                              // 512*64*512*2 = 32 MiB
  size_t off    = (size_t)33554432;
  u16* wbuf     = (u16*)(ws + off);   off += 6291456;    // 128*64*48*16B = 6 MiB
  float* bias_s = (float*)(ws + off); off += 8192;       // 128*16*4
  u32* hbuf     = (u32*)(ws + off);   off += 262144;     // 2*64*512*4
  float* hlast  = (float*)(ws + off); off += 131072;     // 64*512*4
  u32* bar      = (u32*)(ws + off);                      // 128 step slots

  hipMemsetAsync(bar, 0, 2048, stream);                  // reset per launch/replay

  stage_weights<<<dim3(NWG), dim3(64), 0, stream>>>(
      Whr, Whf, Whg, Who, Wir, Wif, Wig, Wio,
      bhr, bhf, bhg, bho, bir, bif, big_, bio, wbuf, bias_s);

  lstm_persist<<<dim3(NWG), dim3(256), 0, stream>>>(
      words, emb, wbuf, bias_s, hbuf, hs, hlast, bar);

  post_kernel<<<dim3(NB), dim3(256), 0, stream>>>(hlast, hs, W_ol, b_ol, W_att, b_att,
                                                  W_fc, b_fc, (float*)d_out);
}